// Round 1
// 1208.115 us; speedup vs baseline: 1.0663x; 1.0663x over previous
//
#include <hip/hip_runtime.h>
#include <hip/hip_bf16.h>
#include <math.h>

#define BB 4
#define SS 2048
#define DD 768
#define HH 12
#define DHD 64
#define FF 3072
#define LL 4

typedef float ffrag __attribute__((ext_vector_type(4)));
typedef __bf16 bf16x8 __attribute__((ext_vector_type(8)));
typedef __bf16 bf16x4 __attribute__((ext_vector_type(4)));

// async global->LDS, 16 B per lane. lds base must be wave-uniform;
// HW writes lds_base + lane*16.
__device__ __forceinline__ void gld_lds16(const __bf16* g, __bf16* l) {
  __builtin_amdgcn_global_load_lds(
      (const __attribute__((address_space(1))) void*)g,
      (__attribute__((address_space(3))) void*)l, 16, 0, 0);
}

// tanh-form GELU via logistic identity: 0.5x(1+tanh(u)) = x * sigmoid(2u).
__device__ __forceinline__ float gelu_f(float x) {
  const float x2 = x * x;
  const float e = __expf(x * fmaf(-0.0713548162f, x2, -1.5957691216f));
  return x / (1.f + e);
}

// ---------------------------------------------------------------------------
// GEMM core: stage A/B tiles (swizzled granules, global_load_lds w=16) and
// run the K-loop. SWAP=1: D = B*A (N on quad*4+reg axis -> packed stores).
// ---------------------------------------------------------------------------
template <int SWAP>
__device__ __forceinline__ void gemm_core(
    const __bf16* __restrict__ A, const __bf16* __restrict__ Bt,
    __bf16* As, __bf16* Bs, int m0, int n0, int K, int kbeg, int kend,
    int lane, int wid, ffrag (&acc)[4][4]) {
  const int kr = lane >> 4;
  const int ml = lane & 15;
  const int wm = (wid >> 1) * 64;
  const int wn = (wid & 1) * 64;
  for (int k0 = kbeg; k0 < kend; k0 += 64) {
    __syncthreads();
#pragma unroll
    for (int it = 0; it < 4; ++it) {
      const int gidx = it * 256 + wid * 64 + lane;
      const int row = gidx >> 3;
      const int gl = (gidx & 7) ^ (row & 7);
      gld_lds16(A + (size_t)(m0 + row) * K + k0 + gl * 8,
                As + (size_t)(it * 256 + wid * 64) * 8);
      gld_lds16(Bt + (size_t)(n0 + row) * K + k0 + gl * 8,
                Bs + (size_t)(it * 256 + wid * 64) * 8);
    }
    __syncthreads();
#pragma unroll
    for (int kh = 0; kh < 2; ++kh) {
      const int gb = kh * 4 + kr;
      bf16x8 af[4], bfr[4];
#pragma unroll
      for (int i = 0; i < 4; ++i) {
        const int ra = wm + i * 16 + ml;
        af[i] = *(const bf16x8*)(As + ra * 64 + ((gb ^ (ra & 7)) * 8));
        const int rb = wn + i * 16 + ml;
        bfr[i] = *(const bf16x8*)(Bs + rb * 64 + ((gb ^ (rb & 7)) * 8));
      }
#pragma unroll
      for (int i = 0; i < 4; ++i)
#pragma unroll
        for (int j = 0; j < 4; ++j) {
          if (SWAP)
            acc[i][j] = __builtin_amdgcn_mfma_f32_16x16x32_bf16(
                bfr[j], af[i], acc[i][j], 0, 0, 0);
          else
            acc[i][j] = __builtin_amdgcn_mfma_f32_16x16x32_bf16(
                af[i], bfr[j], acc[i][j], 0, 0, 0);
        }
    }
  }
}

// ---------------------------------------------------------------------------
// Standard GEMM: C = A @ Bt^T (+bias)(+GELU). Swapped epilogue (packed).
// SPLITK: grid.z in {0,1} computes K-half z, writes Cf + z*M*N (bias z0 only).
// ---------------------------------------------------------------------------
template <int ACT, int WRITE_BF16, int SPLITK>
__global__ __launch_bounds__(256) void gemm_std(
    const __bf16* __restrict__ A, const __bf16* __restrict__ Bt,
    const float* __restrict__ bias, float* __restrict__ Cf,
    __bf16* __restrict__ Cb, int M, int N, int K) {
  __shared__ __bf16 As[128 * 64];
  __shared__ __bf16 Bs[128 * 64];
  const int tid = threadIdx.x;
  const int lane = tid & 63;
  const int wid = tid >> 6;
  const int m0 = blockIdx.y * 128;
  const int n0 = blockIdx.x * 128;
  const int wm = (wid >> 1) * 64;
  const int wn = (wid & 1) * 64;
  const int ml = lane & 15;
  const int quad = lane >> 4;

  int kbeg = 0, kend = K;
  if (SPLITK) {
    const int z = blockIdx.z;
    const int half = K >> 1;
    kbeg = z * half;
    kend = kbeg + half;
    Cf += (size_t)z * M * N;
    if (z) bias = nullptr;
  }

  ffrag acc[4][4];
#pragma unroll
  for (int i = 0; i < 4; ++i)
#pragma unroll
    for (int j = 0; j < 4; ++j) acc[i][j] = (ffrag)0.f;

  gemm_core<1>(A, Bt, As, Bs, m0, n0, K, kbeg, kend, lane, wid, acc);

  // swapped epilogue: row(N)=quad*4+r, col(M)=ml; regs contiguous in N.
#pragma unroll
  for (int j = 0; j < 4; ++j) {
    const int ncol = n0 + wn + j * 16 + quad * 4;
    float4 b4 = make_float4(0.f, 0.f, 0.f, 0.f);
    if (bias) b4 = *(const float4*)(bias + ncol);
#pragma unroll
    for (int i = 0; i < 4; ++i) {
      const int mrow = m0 + wm + i * 16 + ml;
      float v0 = acc[i][j][0] + b4.x;
      float v1 = acc[i][j][1] + b4.y;
      float v2 = acc[i][j][2] + b4.z;
      float v3 = acc[i][j][3] + b4.w;
      if (ACT) {
        v0 = gelu_f(v0); v1 = gelu_f(v1);
        v2 = gelu_f(v2); v3 = gelu_f(v3);
      }
      if (WRITE_BF16) {
        bf16x4 pk;
        pk[0] = (__bf16)v0; pk[1] = (__bf16)v1;
        pk[2] = (__bf16)v2; pk[3] = (__bf16)v3;
        *(bf16x4*)(Cb + (size_t)mrow * N + ncol) = pk;
      } else {
        float4 o; o.x = v0; o.y = v1; o.z = v2; o.w = v3;
        *(float4*)(Cf + (size_t)mrow * N + ncol) = o;
      }
    }
  }
}

// ---------------------------------------------------------------------------
// Merged QKV projection, grid (18, 64). Blocks with n0<1536 compute q,k
// (swapped epilogue, packed stores to QKb ld 1536); n0>=1536 compute v
// (normal orientation, packed along s into Vt [B][H][64][S]).
// ---------------------------------------------------------------------------
__global__ __launch_bounds__(256) void gemm_qkv(
    const __bf16* __restrict__ A, const __bf16* __restrict__ Bt,
    __bf16* __restrict__ QKb, __bf16* __restrict__ Vt, int M, int K) {
  __shared__ __bf16 As[128 * 64];
  __shared__ __bf16 Bs[128 * 64];
  const int tid = threadIdx.x;
  const int lane = tid & 63;
  const int wid = tid >> 6;
  const int m0 = blockIdx.y * 128;
  const int n0 = blockIdx.x * 128;
  const int wm = (wid >> 1) * 64;
  const int wn = (wid & 1) * 64;
  const int ml = lane & 15;
  const int quad = lane >> 4;

  ffrag acc[4][4];
#pragma unroll
  for (int i = 0; i < 4; ++i)
#pragma unroll
    for (int j = 0; j < 4; ++j) acc[i][j] = (ffrag)0.f;

  if (n0 < 1536) {
    gemm_core<1>(A, Bt, As, Bs, m0, n0, K, 0, K, lane, wid, acc);
#pragma unroll
    for (int j = 0; j < 4; ++j) {
      const int ncol = n0 + wn + j * 16 + quad * 4;
#pragma unroll
      for (int i = 0; i < 4; ++i) {
        const int mrow = m0 + wm + i * 16 + ml;
        bf16x4 pk;
#pragma unroll
        for (int r = 0; r < 4; ++r) pk[r] = (__bf16)acc[i][j][r];
        *(bf16x4*)(QKb + (size_t)mrow * 1536 + ncol) = pk;
      }
    }
  } else {
    gemm_core<0>(A, Bt, As, Bs, m0, n0, K, 0, K, lane, wid, acc);
#pragma unroll
    for (int j = 0; j < 4; ++j) {
      const int vcol = n0 - 1536 + wn + j * 16 + ml;
      const int hh = vcol >> 6, d = vcol & 63;
#pragma unroll
      for (int i = 0; i < 4; ++i) {
        const int row = m0 + wm + i * 16 + quad * 4;
        const int bi = row >> 11, s = row & 2047;
        bf16x4 pk;
#pragma unroll
        for (int r = 0; r < 4; ++r) pk[r] = (__bf16)acc[i][j][r];
        *(bf16x4*)(Vt + ((size_t)(bi * HH + hh) * DHD + d) * SS + s) = pk;
      }
    }
  }
}

// ---------------------------------------------------------------------------
// weight prep: src fp32 [L][R][C] -> dst bf16 [L][C][R], blockIdx.z = layer
// ---------------------------------------------------------------------------
__global__ __launch_bounds__(256) void wtrans_kernel(
    const float* __restrict__ src, __bf16* __restrict__ dst, int R, int C,
    size_t src_ls, size_t dst_ls) {
  __shared__ float t[32][33];
  src += (size_t)blockIdx.z * src_ls;
  dst += (size_t)blockIdx.z * dst_ls;
  const int tx = threadIdx.x & 31;
  const int ty = threadIdx.x >> 5;
  const int r0 = blockIdx.y * 32;
  const int c0 = blockIdx.x * 32;
#pragma unroll
  for (int i = 0; i < 4; ++i)
    t[ty + i * 8][tx] = src[(size_t)(r0 + ty + i * 8) * C + c0 + tx];
  __syncthreads();
#pragma unroll
  for (int i = 0; i < 4; ++i)
    dst[(size_t)(c0 + ty + i * 8) * R + r0 + tx] = (__bf16)t[tx][ty + i * 8];
}

// fp32 -> bf16 elementwise
__global__ __launch_bounds__(256) void cvt_kernel(
    const float* __restrict__ x, __bf16* __restrict__ y, int n4) {
  const int i = blockIdx.x * 256 + threadIdx.x;
  if (i < n4) {
    const float4 v = *(const float4*)(x + (size_t)i * 4);
    bf16x4 o;
    o[0] = (__bf16)v.x; o[1] = (__bf16)v.y;
    o[2] = (__bf16)v.z; o[3] = (__bf16)v.w;
    *(bf16x4*)(y + (size_t)i * 4) = o;
  }
}

// ---------------------------------------------------------------------------
// MFMA flash attention: TQ=64, balanced pairs, double-buffered K/V,
// S^T trick, no running max. LDS 49 KB -> 3 blocks/CU.
// R0 change: XCD-aware bijective block swizzle. All 768 blocks are
// co-resident (256 CU x 3); default round-robin spreads the 16 q-tile
// blocks sharing one (b,h)'s K/V (512 KB) across all 8 XCD L2s ->
// 8x K/V refetch (measured 188 MB/dispatch ~= 48*8*512KB). Swizzle
// sw = (flat&7)*96 + flat>>3 gives each XCD 6 whole (b,h) groups
// (3 MB < 4 MB L2). Pure block renaming; bijective since 768 = 8*96.
// ---------------------------------------------------------------------------
__global__ __launch_bounds__(256, 3) void attn_mfma(
    const __bf16* __restrict__ QK, const __bf16* __restrict__ VT,
    __bf16* __restrict__ O) {
  __shared__ __bf16 qs[64 * 64];
  __shared__ __bf16 ks[2][64 * 64];
  __shared__ __bf16 vts[2][64 * 64];
  __shared__ __bf16 ps[64 * 72];

  const int flat = (int)blockIdx.x + 16 * ((int)blockIdx.y + 12 * (int)blockIdx.z);
  const int sw = (flat & 7) * 96 + (flat >> 3);
  const int xq = sw & 15;   // q-tile-pair index (fastest -> contiguous per bh)
  const int bh = sw >> 4;   // 0..47
  const int h = bh % HH;
  const int b = bh / HH;

  const int tid = threadIdx.x;
  const int lane = tid & 63;
  const int wid = tid >> 6;
  const int ml = lane & 15;
  const int quad = lane >> 4;
  const int wq = wid * 16;
  const size_t rowbase = (size_t)b * SS;
  const int hc = h * 64;
  const size_t vbase = (size_t)(b * HH + h) * DHD;
  const int NT = SS / 64;

  const int gidx0 = wid * 64 + lane;
  const int row0 = gidx0 >> 3;
  const int gl0 = (gidx0 & 7) ^ (row0 & 7);
  const int gidx1 = 256 + wid * 64 + lane;
  const int row1 = gidx1 >> 3;
  const int gl1 = (gidx1 & 7) ^ (row1 & 7);

  for (int ph = 0; ph < 2; ++ph) {
    const int qt = ph ? (NT - 1 - xq) : xq;
    const int q0 = qt * 64;

    __syncthreads();

    gld_lds16(QK + (rowbase + q0 + row0) * 1536 + hc + gl0 * 8,
              qs + (size_t)(wid * 64) * 8);
    gld_lds16(QK + (rowbase + q0 + row1) * 1536 + hc + gl1 * 8,
              qs + (size_t)(256 + wid * 64) * 8);
    gld_lds16(QK + (rowbase + row0) * 1536 + 768 + hc + gl0 * 8,
              ks[0] + (size_t)(wid * 64) * 8);
    gld_lds16(QK + (rowbase + row1) * 1536 + 768 + hc + gl1 * 8,
              ks[0] + (size_t)(256 + wid * 64) * 8);
    gld_lds16(VT + (vbase + row0) * SS + gl0 * 8, vts[0] + (size_t)(wid * 64) * 8);
    gld_lds16(VT + (vbase + row1) * SS + gl1 * 8, vts[0] + (size_t)(256 + wid * 64) * 8);

    ffrag oacc[4];
#pragma unroll
    for (int d = 0; d < 4; ++d) oacc[d] = (ffrag)0.f;
    float l_acc = 0.f;

    for (int ch = 0; ch <= qt; ++ch) {
      const int j0 = ch * 64;
      const int cur = ch & 1;
      __syncthreads();

      if (ch < qt) {
        const int jn = j0 + 64;
        gld_lds16(QK + (rowbase + jn + row0) * 1536 + 768 + hc + gl0 * 8,
                  ks[cur ^ 1] + (size_t)(wid * 64) * 8);
        gld_lds16(QK + (rowbase + jn + row1) * 1536 + 768 + hc + gl1 * 8,
                  ks[cur ^ 1] + (size_t)(256 + wid * 64) * 8);
        gld_lds16(VT + (vbase + row0) * SS + jn + gl0 * 8,
                  vts[cur ^ 1] + (size_t)(wid * 64) * 8);
        gld_lds16(VT + (vbase + row1) * SS + jn + gl1 * 8,
                  vts[cur ^ 1] + (size_t)(256 + wid * 64) * 8);
      }

      ffrag sa[4];
#pragma unroll
      for (int jt = 0; jt < 4; ++jt) sa[jt] = (ffrag)0.f;
#pragma unroll
      for (int kk = 0; kk < 2; ++kk) {
        const int gb = kk * 4 + quad;
        const int ra = wq + ml;
        const bf16x8 qf = *(const bf16x8*)(qs + ra * 64 + ((gb ^ (ra & 7)) * 8));
#pragma unroll
        for (int jt = 0; jt < 4; ++jt) {
          const int rb = jt * 16 + ml;
          const bf16x8 kf =
              *(const bf16x8*)(ks[cur] + rb * 64 + ((gb ^ (rb & 7)) * 8));
          sa[jt] = __builtin_amdgcn_mfma_f32_16x16x32_bf16(kf, qf, sa[jt], 0, 0, 0);
        }
      }

      const bool maskch = (j0 == q0);
      const int qrel = wq + ml;
      float lsum = 0.f;
      bf16x4 pk[4];
#pragma unroll
      for (int jt = 0; jt < 4; ++jt) {
#pragma unroll
        for (int r = 0; r < 4; ++r) {
          float p = __expf(sa[jt][r] * 0.125f);
          if (maskch && (jt * 16 + quad * 4 + r > qrel)) p = 0.f;
          lsum += p;
          pk[jt][r] = (__bf16)p;
        }
      }
      lsum += __shfl_xor(lsum, 16);
      lsum += __shfl_xor(lsum, 32);
      l_acc += lsum;

#pragma unroll
      for (int jt = 0; jt < 4; ++jt)
        *(bf16x4*)(ps + (size_t)(wq + ml) * 72 + jt * 16 + quad * 4) = pk[jt];

#pragma unroll
      for (int kk = 0; kk < 2; ++kk) {
        const bf16x8 ap =
            *(const bf16x8*)(ps + (size_t)(wq + ml) * 72 + kk * 32 + quad * 8);
        const int gb = kk * 4 + quad;
#pragma unroll
        for (int d = 0; d < 4; ++d) {
          const int rv = d * 16 + ml;
          const bf16x8 bv =
              *(const bf16x8*)(vts[cur] + rv * 64 + ((gb ^ (rv & 7)) * 8));
          oacc[d] = __builtin_amdgcn_mfma_f32_16x16x32_bf16(ap, bv, oacc[d], 0, 0, 0);
        }
      }
    }

#pragma unroll
    for (int r = 0; r < 4; ++r) {
      const int qloc = quad * 4 + r;
      const float lr = __shfl(l_acc, qloc);
      const float inv = 1.f / lr;
      const size_t row = rowbase + q0 + wq + qloc;
#pragma unroll
      for (int d = 0; d < 4; ++d)
        O[row * DD + hc + d * 16 + ml] = (__bf16)(oacc[d][r] * inv);
    }
  }
}

// ---------------------------------------------------------------------------
// Out = LayerNorm(X + R1 [+ R2])*g + b over last dim (768).
// X is bf16 (residual stream); R1/R2 fp32 (GEMM partials). Optional fp32
// and/or bf16 outputs (null -> skip). Branches are launch-uniform.
// ---------------------------------------------------------------------------
__global__ __launch_bounds__(256) void add_ln_kernel(
    const __bf16* __restrict__ X, const float* __restrict__ R1,
    const float* __restrict__ R2, const float* __restrict__ g,
    const float* __restrict__ be, float* __restrict__ Ofp,
    __bf16* __restrict__ Ob) {
  const int row = blockIdx.x * 4 + (threadIdx.x >> 6);
  const int lane = threadIdx.x & 63;
  const __bf16* xr = X + (size_t)row * DD;
  const float* r1 = R1 + (size_t)row * DD;
  const float* r2 = R2 ? R2 + (size_t)row * DD : nullptr;
  float v[12];
  float sum = 0.f;
#pragma unroll
  for (int i = 0; i < 3; ++i) {
    const int c = i * 256 + lane * 4;
    const bf16x4 a = *(const bf16x4*)(xr + c);
    const float4 b = *(const float4*)(r1 + c);
    float4 c2 = make_float4(0.f, 0.f, 0.f, 0.f);
    if (r2) c2 = *(const float4*)(r2 + c);
    v[i * 4 + 0] = (float)a[0] + b.x + c2.x;
    v[i * 4 + 1] = (float)a[1] + b.y + c2.y;
    v[i * 4 + 2] = (float)a[2] + b.z + c2.z;
    v[i * 4 + 3] = (float)a[3] + b.w + c2.w;
    sum += v[i * 4 + 0] + v[i * 4 + 1] + v[i * 4 + 2] + v[i * 4 + 3];
  }
#pragma unroll
  for (int off = 32; off >= 1; off >>= 1) sum += __shfl_xor(sum, off);
  const float mean = sum * (1.f / 768.f);
  float sq = 0.f;
#pragma unroll
  for (int i = 0; i < 12; ++i) {
    const float d = v[i] - mean;
    sq += d * d;
  }
#pragma unroll
  for (int off = 32; off >= 1; off >>= 1) sq += __shfl_xor(sq, off);
  const float inv = rsqrtf(sq * (1.f / 768.f) + 1e-5f);
#pragma unroll
  for (int i = 0; i < 3; ++i) {
    const int c = i * 256 + lane * 4;
    const float4 gg = *(const float4*)(g + c);
    const float4 bb = *(const float4*)(be + c);
    float4 o;
    o.x = (v[i * 4 + 0] - mean) * inv * gg.x + bb.x;
    o.y = (v[i * 4 + 1] - mean) * inv * gg.y + bb.y;
    o.z = (v[i * 4 + 2] - mean) * inv * gg.z + bb.z;
    o.w = (v[i * 4 + 3] - mean) * inv * gg.w + bb.w;
    if (Ofp) *(float4*)(Ofp + (size_t)row * DD + c) = o;
    if (Ob) {
      bf16x4 ob;
      ob[0] = (__bf16)o.x; ob[1] = (__bf16)o.y;
      ob[2] = (__bf16)o.z; ob[3] = (__bf16)o.w;
      *(bf16x4*)(Ob + (size_t)row * DD + c) = ob;
    }
  }
}

// ---------------------------------------------------------------------------
extern "C" void kernel_launch(void* const* d_in, const int* in_sizes, int n_in,
                              void* d_out, int out_size, void* d_ws,
                              size_t ws_size, hipStream_t stream) {
  const float* x0   = (const float*)d_in[0];
  const float* Wq   = (const float*)d_in[2];
  const float* Wk   = (const float*)d_in[3];
  const float* Wv   = (const float*)d_in[4];
  const float* Wo   = (const float*)d_in[5];
  const float* bo   = (const float*)d_in[6];
  const float* ln1g = (const float*)d_in[7];
  const float* ln1b = (const float*)d_in[8];
  const float* W1   = (const float*)d_in[9];
  const float* b1   = (const float*)d_in[10];
  const float* W2   = (const float*)d_in[11];
  const float* b2   = (const float*)d_in[12];
  const float* ln2g = (const float*)d_in[13];
  const float* ln2b = (const float*)d_in[14];

  float* out = (float*)d_out;

  // workspace carve-up (~170 MB); residual stream xbf lives in d_out's
  // first half (bf16), fully overwritten by the final fp32 LN at layer 3.
  const size_t NTD = (size_t)BB * SS * DD;       // 6,291,456
  __bf16* qkbf = (__bf16*)d_ws;                  // [M][1536] q,k (12.58M)
  __bf16* vtbf = qkbf + (size_t)BB * SS * 1536;  // [B][H][64][S] (6.29M)
  __bf16* btbf = vtbf + NTD;                     // attn out bf16 (6.29M)
  __bf16* midbf = qkbf;   // ffn hidden [M][3072] = qk+vt+bt = 25.17M exactly
  __bf16* hbf  = btbf + NTD;                     // ln1 out bf16
  float* aw    = (float*)(hbf + NTD);            // 2x fp32 partials [2][M][768]
  __bf16* wT   = (__bf16*)(aw + 2 * NTD);        // all-layer W^T bf16
  __bf16* xbf  = (__bf16*)d_out;                 // residual stream bf16

  const size_t WTL = 7077888;  // per-layer: 2304*768 + 768*768 + 2*3072*768
  const size_t OQK = 0, OWO = (size_t)2304 * 768, OW1 = 2359296, OW2 = 4718592;

  const int M = BB * SS;  // 8192
  const size_t DSQ = (size_t)DD * DD;

  cvt_kernel<<<(int)(NTD / 4 + 255) / 256, 256, 0, stream>>>(x0, xbf, (int)(NTD / 4));

  // all-layer weight prep: fp32 [L][K][N] -> bf16 [L][N][K]
  wtrans_kernel<<<dim3(24, 24, LL), 256, 0, stream>>>(Wq, wT + OQK, DD, DD, DSQ, WTL);
  wtrans_kernel<<<dim3(24, 24, LL), 256, 0, stream>>>(Wk, wT + (size_t)768 * 768, DD, DD, DSQ, WTL);
  wtrans_kernel<<<dim3(24, 24, LL), 256, 0, stream>>>(Wv, wT + (size_t)1536 * 768, DD, DD, DSQ, WTL);
  wtrans_kernel<<<dim3(24, 24, LL), 256, 0, stream>>>(Wo, wT + OWO, DD, DD, DSQ, WTL);
  wtrans_kernel<<<dim3(96, 24, LL), 256, 0, stream>>>(W1, wT + OW1, DD, FF, (size_t)DD * FF, WTL);
  wtrans_kernel<<<dim3(24, 96, LL), 256, 0, stream>>>(W2, wT + OW2, FF, DD, (size_t)FF * DD, WTL);

  for (int l = 0; l < LL; ++l) {
    const float* bol = bo + (size_t)l * DD;
    const float* g1 = ln1g + (size_t)l * DD;
    const float* be1 = ln1b + (size_t)l * DD;
    const float* b1l = b1 + (size_t)l * FF;
    const float* b2l = b2 + (size_t)l * DD;
    const float* g2 = ln2g + (size_t)l * DD;
    const float* be2 = ln2b + (size_t)l * DD;
    __bf16* wqkvT = wT + l * WTL + OQK;
    __bf16* woT   = wT + l * WTL + OWO;
    __bf16* w1T   = wT + l * WTL + OW1;
    __bf16* w2T   = wT + l * WTL + OW2;
    const bool last = (l == LL - 1);

    // merged q,k,v projection: qk -> qkbf [M][1536], v -> vtbf (transposed)
    gemm_qkv<<<dim3(18, 64), 256, 0, stream>>>(xbf, wqkvT, qkbf, vtbf, M, DD);
    // MFMA flash attention (paired q-tiles, double-buffered K/V) -> btbf
    attn_mfma<<<dim3(SS / 128, HH, BB), 256, 0, stream>>>(qkbf, vtbf, btbf);
    // output projection + bias -> aw[0] fp32
    gemm_std<0, 0, 0><<<dim3(6, 64), 256, 0, stream>>>(
        btbf, woT, bol, aw, nullptr, M, DD, DD);
    // h = LN(x + attn_out) -> hbf bf16
    add_ln_kernel<<<M / 4, 256, 0, stream>>>(
        xbf, aw, nullptr, g1, be1, nullptr, hbf);
    // ffn hidden = gelu(h@W1 + b1) -> midbf bf16 (aliases qk/vt/bt; all dead)
    gemm_std<1, 1, 0><<<dim3(24, 64), 256, 0, stream>>>(
        hbf, w1T, b1l, nullptr, midbf, M, FF, DD);
    // ffn out = mid@W2 + b2 -> split-K partials aw[0], aw[1]
    gemm_std<0, 0, 1><<<dim3(6, 64, 2), 256, 0, stream>>>(
        midbf, w2T, b2l, aw, nullptr, M, DD, FF);
    // out = LN(h + f0 + f1): last layer -> fp32 d_out; else -> bf16 xbf
    add_ln_kernel<<<M / 4, 256, 0, stream>>>(
        hbf, aw, aw + NTD, g2, be2, last ? out : nullptr, last ? nullptr : xbf);
  }
}